// Round 5
// baseline (200.208 us; speedup 1.0000x reference)
//
#include <hip/hip_runtime.h>

// Problem constants (from reference)
#define BB 16
#define TT 4096
#define HH 64
#define DD 10
#define MM 640    // HH*DD

#define TROWS 16          // t-rows per attn tile
#define PADF4 41          // LDS row stride in float4 (656 B; 16B-aligned, banks spread)
#define NBLK 1792         // persistent attn grid: 7 blocks/CU * 256 CU
#define NTILE (256 * 4 * BB)   // 16384 tiles: 256 t-tiles x 4 head-groups x 16 b

// ---------------------------------------------------------------------------
// Kernel 0: zero the ksum workspace (B*M floats = 40 KB)
// ---------------------------------------------------------------------------
__global__ void zero_ws_kernel(float* __restrict__ ws, int n) {
    int i = blockIdx.x * blockDim.x + threadIdx.x;
    if (i < n) ws[i] = 0.0f;
}

// ---------------------------------------------------------------------------
// Kernel 1: ksum[b][m] = sum_t key[b][t][m]   (~27 us, BW-bound -- unchanged)
// ---------------------------------------------------------------------------
__global__ void __launch_bounds__(256)
ksum_kernel(const float* __restrict__ key, float* __restrict__ ksum) {
    int g = blockIdx.x * blockDim.x + threadIdx.x;   // 0..2559 = b*160 + c
    int b = g / 160;
    int c = g % 160;
    int t0 = blockIdx.y * 32;

    const float4* p = reinterpret_cast<const float4*>(key)
                    + (size_t)b * TT * 160 + (size_t)t0 * 160 + c;

    float4 a0 = make_float4(0.f,0.f,0.f,0.f);
    float4 a1 = make_float4(0.f,0.f,0.f,0.f);
    float4 a2 = make_float4(0.f,0.f,0.f,0.f);
    float4 a3 = make_float4(0.f,0.f,0.f,0.f);
    #pragma unroll
    for (int i = 0; i < 32; i += 4) {
        float4 x0 = p[(size_t)(i + 0) * 160];
        float4 x1 = p[(size_t)(i + 1) * 160];
        float4 x2 = p[(size_t)(i + 2) * 160];
        float4 x3 = p[(size_t)(i + 3) * 160];
        a0.x += x0.x; a0.y += x0.y; a0.z += x0.z; a0.w += x0.w;
        a1.x += x1.x; a1.y += x1.y; a1.z += x1.z; a1.w += x1.w;
        a2.x += x2.x; a2.y += x2.y; a2.z += x2.z; a2.w += x2.w;
        a3.x += x3.x; a3.y += x3.y; a3.z += x3.z; a3.w += x3.w;
    }
    float sx = (a0.x + a1.x) + (a2.x + a3.x);
    float sy = (a0.y + a1.y) + (a2.y + a3.y);
    float sz = (a0.z + a1.z) + (a2.z + a3.z);
    float sw = (a0.w + a1.w) + (a2.w + a3.w);

    float* dst = ksum + b * MM + c * 4;
    atomicAdd(dst + 0, sx);
    atomicAdd(dst + 1, sy);
    atomicAdd(dst + 2, sz);
    atomicAdd(dst + 3, sw);
}

// ---------------------------------------------------------------------------
// Robust tanh via rcp (no overflow, no IEEE divide chain)
// ---------------------------------------------------------------------------
__device__ __forceinline__ float tanh_rcp(float x) {
    float ax = fabsf(x);
    float e2 = __expf(-2.0f * ax);                          // (0,1]
    float th = (1.0f - e2) * __builtin_amdgcn_rcpf(1.0f + e2);
    return copysignf(th, x);
}

// ---------------------------------------------------------------------------
// Kernel 2: persistent, software-pipelined.
// Per iteration: sync / LDS-write regs / sync / ISSUE next-tile loads /
// compute current tile / store. Next-tile HBM loads fly during compute,
// so the memory system never idles (fixes the phase-lockstep 4.2 TB/s).
// ---------------------------------------------------------------------------
__global__ void __launch_bounds__(128)
attn_kernel(const float* __restrict__ q,
            const float* __restrict__ v,
            const float* __restrict__ ksum,
            float* __restrict__ out) {
    __shared__ float4 qs[TROWS * PADF4];
    __shared__ float4 vs[TROWS * PADF4];

    const int tid = threadIdx.x;          // 0..127
    const int bid = blockIdx.x;

    int rows[5], cols[5];
    #pragma unroll
    for (int i = 0; i < 5; ++i) {
        int idx = tid + 128 * i;          // 0..639
        rows[i] = idx / 40;
        cols[i] = idx % 40;
    }
    const int head0 = tid >> 4;           // o=0 head (0..7)
    const int row   = tid & 15;

    const float R = 0.316227766016838f;   // 1/sqrt(10)

    float4 rq[5], rv[5];
    // ---- prologue: load tile vt = bid into regs ----
    {
        int t0 = (bid & 255) * TROWS;
        int hg = (bid >> 8) & 3;
        int b  = bid >> 10;
        const float4* qg = reinterpret_cast<const float4*>(q)
                         + ((size_t)(b * TT + t0)) * 160 + hg * 40;
        const float4* vg = reinterpret_cast<const float4*>(v)
                         + ((size_t)(b * TT + t0)) * 160 + hg * 40;
        #pragma unroll
        for (int i = 0; i < 5; ++i) {
            rq[i] = qg[(size_t)rows[i] * 160 + cols[i]];
            rv[i] = vg[(size_t)rows[i] * 160 + cols[i]];
        }
    }

    for (int vt = bid; vt < NTILE; vt += NBLK) {
        const int t0 = (vt & 255) * TROWS;
        const int hg = (vt >> 8) & 3;
        const int b  = vt >> 10;

        // preload this tile's ksum rows for both outputs (L1/L2-hot, 40 KB table)
        const float* ks0 = ksum + b * MM + hg * 160 + head0 * 10;
        const float* ks1 = ks0 + 80;                 // head1 = head0 + 8
        float2 kk0[5], kk1[5];
        #pragma unroll
        for (int i = 0; i < 5; ++i) {
            kk0[i] = *reinterpret_cast<const float2*>(ks0 + 2 * i);
            kk1[i] = *reinterpret_cast<const float2*>(ks1 + 2 * i);
        }

        __syncthreads();                  // all threads done reading prev tile
        #pragma unroll
        for (int i = 0; i < 5; ++i) {
            qs[rows[i] * PADF4 + cols[i]] = rq[i];
            vs[rows[i] * PADF4 + cols[i]] = rv[i];
        }
        __syncthreads();                  // tile visible

        // ---- issue next tile's loads NOW (no wait) ----
        int vn = vt + NBLK;
        if (vn < NTILE) {
            int t0n = (vn & 255) * TROWS;
            int hgn = (vn >> 8) & 3;
            int bn  = vn >> 10;
            const float4* qg = reinterpret_cast<const float4*>(q)
                             + ((size_t)(bn * TT + t0n)) * 160 + hgn * 40;
            const float4* vg = reinterpret_cast<const float4*>(v)
                             + ((size_t)(bn * TT + t0n)) * 160 + hgn * 40;
            #pragma unroll
            for (int i = 0; i < 5; ++i) {
                rq[i] = qg[(size_t)rows[i] * 160 + cols[i]];
                rv[i] = vg[(size_t)rows[i] * 160 + cols[i]];
            }
        }

        // ---- compute 2 outputs from LDS while next tile streams in ----
        const float* qsf = reinterpret_cast<const float*>(qs);
        const float* vsf = reinterpret_cast<const float*>(vs);
        #pragma unroll
        for (int o = 0; o < 2; ++o) {
            const int head  = head0 + o * 8;
            const int lbase = row * (PADF4 * 4) + head * 10;
            const float2* kk = o ? kk1 : kk0;
            float sum = 0.f, dot = 0.f;
            #pragma unroll
            for (int i = 0; i < 5; ++i) {
                float e0 = __expf(tanh_rcp(qsf[lbase + 2*i]     * kk[i].x * R));
                float e1 = __expf(tanh_rcp(qsf[lbase + 2*i + 1] * kk[i].y * R));
                sum += e0 + e1;
                dot += e0 * vsf[lbase + 2*i] + e1 * vsf[lbase + 2*i + 1];
            }
            out[((size_t)(b * HH + hg * 16 + head)) * TT + t0 + row]
                = dot * __builtin_amdgcn_rcpf(sum);
        }
    }
}

// ---------------------------------------------------------------------------
extern "C" void kernel_launch(void* const* d_in, const int* in_sizes, int n_in,
                              void* d_out, int out_size, void* d_ws, size_t ws_size,
                              hipStream_t stream) {
    const float* q = (const float*)d_in[0];
    const float* k = (const float*)d_in[1];
    const float* v = (const float*)d_in[2];
    // d_in[3] = W, d_in[4] = b : dead code (softmax over size-1 axis == 1)
    float* out  = (float*)d_out;
    float* ksum = (float*)d_ws;    // B*M floats = 40 KB

    zero_ws_kernel<<<dim3((BB * MM + 255) / 256), dim3(256), 0, stream>>>(ksum, BB * MM);
    ksum_kernel<<<dim3(10, 128), dim3(256), 0, stream>>>(k, ksum);
    attn_kernel<<<dim3(NBLK), dim3(128), 0, stream>>>(q, v, ksum, out);
}

// Round 6
// 131.034 us; speedup vs baseline: 1.5279x; 1.5279x over previous
//
#include <hip/hip_runtime.h>
#include <stdint.h>

// Problem constants
#define BB 16
#define TT 4096
#define HH 64
#define MM 640     // HH*DD

// attn geometry
#define TROWS 8               // t-rows per tile (one head-group of 16 heads)
#define NTT   (TT / TROWS)    // 512 t-tiles per (b,hg)
#define SUBS  32              // blocks per (b,hg) combo
#define NBLK  (64 * SUBS)     // 2048 = 8 blocks/CU * 256 CU, 64 combos

// ---------------------------------------------------------------------------
// Kernel 0: zero the ksum workspace
// ---------------------------------------------------------------------------
__global__ void zero_ws_kernel(float* __restrict__ ws, int n) {
    int i = blockIdx.x * blockDim.x + threadIdx.x;
    if (i < n) ws[i] = 0.0f;
}

// ---------------------------------------------------------------------------
// Kernel 1: ksum[b][m] = sum_t key[b][t][m]  (~27 us ~= read roofline)
// ---------------------------------------------------------------------------
__global__ void __launch_bounds__(256)
ksum_kernel(const float* __restrict__ key, float* __restrict__ ksum) {
    int g = blockIdx.x * blockDim.x + threadIdx.x;   // b*160 + c
    int b = g / 160;
    int c = g % 160;
    int t0 = blockIdx.y * 32;

    const float4* p = reinterpret_cast<const float4*>(key)
                    + (size_t)b * TT * 160 + (size_t)t0 * 160 + c;

    float4 a0 = make_float4(0.f,0.f,0.f,0.f);
    float4 a1 = make_float4(0.f,0.f,0.f,0.f);
    float4 a2 = make_float4(0.f,0.f,0.f,0.f);
    float4 a3 = make_float4(0.f,0.f,0.f,0.f);
    #pragma unroll
    for (int i = 0; i < 32; i += 4) {
        float4 x0 = p[(size_t)(i + 0) * 160];
        float4 x1 = p[(size_t)(i + 1) * 160];
        float4 x2 = p[(size_t)(i + 2) * 160];
        float4 x3 = p[(size_t)(i + 3) * 160];
        a0.x += x0.x; a0.y += x0.y; a0.z += x0.z; a0.w += x0.w;
        a1.x += x1.x; a1.y += x1.y; a1.z += x1.z; a1.w += x1.w;
        a2.x += x2.x; a2.y += x2.y; a2.z += x2.z; a2.w += x2.w;
        a3.x += x3.x; a3.y += x3.y; a3.z += x3.z; a3.w += x3.w;
    }
    float sx = (a0.x + a1.x) + (a2.x + a3.x);
    float sy = (a0.y + a1.y) + (a2.y + a3.y);
    float sz = (a0.z + a1.z) + (a2.z + a3.z);
    float sw = (a0.w + a1.w) + (a2.w + a3.w);

    float* dst = ksum + b * MM + c * 4;
    atomicAdd(dst + 0, sx);
    atomicAdd(dst + 1, sy);
    atomicAdd(dst + 2, sz);
    atomicAdd(dst + 3, sw);
}

// ---------------------------------------------------------------------------
// Robust tanh via rcp (no overflow: exp of negative arg only)
// ---------------------------------------------------------------------------
__device__ __forceinline__ float tanh_rcp(float x) {
    float ax = fabsf(x);
    float e2 = __expf(-2.0f * ax);
    float th = (1.0f - e2) * __builtin_amdgcn_rcpf(1.0f + e2);
    return copysignf(th, x);
}

// async 16B global -> LDS (wave-uniform LDS base + lane*16)
__device__ __forceinline__ void async_cp16(const float4* g, void* l) {
    __builtin_amdgcn_global_load_lds(
        (const __attribute__((address_space(1))) uint32_t*)g,
        (__attribute__((address_space(3))) uint32_t*)l,
        16, 0, 0);
}

// ---------------------------------------------------------------------------
// Kernel 2: persistent 1-wave blocks, barrier-free async pipeline.
//   block -> fixed (b, hg); strides over t-tiles (16 iterations exactly).
//   per iter: issue 10 global_load_lds for next tile -> s_waitcnt vmcnt(10)
//   -> compute current LDS buffer -> 2 stores. Loads always in flight.
//   LDS XOR-swizzle: linear LDS dest (required by global_load_lds), swizzled
//   GLOBAL source (c4'^row) + swizzled read index ((c)^(row<<2)).
// ---------------------------------------------------------------------------
__global__ void __launch_bounds__(64)
attn_kernel(const float* __restrict__ q,
            const float* __restrict__ v,
            const float* __restrict__ ksum,
            float* __restrict__ out) {
    __shared__ float4 lds[2][640];     // [buf][ q:0..319 | v:320..639 ]

    const int lane = threadIdx.x;      // 0..63
    const int bid  = blockIdx.x;
    const int sub   = bid & (SUBS - 1);
    const int combo = bid >> 5;        // 0..63
    const int b  = combo >> 2;
    const int hg = combo & 3;

    // staging source offsets (float4 units within tile), pre-swizzled
    int srcoff[5];
    #pragma unroll
    for (int i = 0; i < 5; ++i) {
        int s = i * 64 + lane;         // LDS f4 slot 0..319
        int r = s / 40;                // tile row
        srcoff[i] = r * 160 + ((s % 40) ^ r);
    }

    const int row   = lane & 7;
    const int head0 = lane >> 3;       // 0..7 (second head = +8)

    const float4* qbase = (const float4*)q + (size_t)b * TT * 160 + hg * 40;
    const float4* vbase = (const float4*)v + (size_t)b * TT * 160 + hg * 40;

    // hoist ksum*R into registers: zero vmem ops from ksum in steady state
    const float R = 0.316227766016838f;   // 1/sqrt(10)
    float ksr[2][10];
    #pragma unroll
    for (int o = 0; o < 2; ++o) {
        const float* ks = ksum + b * MM + hg * 160 + (head0 + 8 * o) * 10;
        #pragma unroll
        for (int d = 0; d < 10; ++d) ksr[o][d] = ks[d] * R;
    }

    float* obase0 = out + ((size_t)(b * HH + hg * 16 + head0)) * TT + row;
    float* obase1 = obase0 + (size_t)8 * TT;

    // prologue: stage first tile into buf 0
    {
        const float4* qt = qbase + (size_t)sub * 1280;   // 8 rows * 160 f4
        const float4* vt = vbase + (size_t)sub * 1280;
        #pragma unroll
        for (int i = 0; i < 5; ++i)
            async_cp16(qt + srcoff[i], (char*)&lds[0][0] + i * 1024);
        #pragma unroll
        for (int i = 0; i < 5; ++i)
            async_cp16(vt + srcoff[i], (char*)&lds[0][320] + i * 1024);
    }

    int buf = 0;
    for (int tt = sub; tt < NTT; tt += SUBS) {
        int ttn = tt + SUBS;
        if (ttn < NTT) {
            const float4* qt = qbase + (size_t)ttn * 1280;
            const float4* vt = vbase + (size_t)ttn * 1280;
            #pragma unroll
            for (int i = 0; i < 5; ++i)
                async_cp16(qt + srcoff[i], (char*)&lds[buf ^ 1][0] + i * 1024);
            #pragma unroll
            for (int i = 0; i < 5; ++i)
                async_cp16(vt + srcoff[i], (char*)&lds[buf ^ 1][320] + i * 1024);
            asm volatile("s_waitcnt vmcnt(10)" ::: "memory");  // cur tile done; next 10 in flight
        } else {
            asm volatile("s_waitcnt vmcnt(0)" ::: "memory");   // final tile
        }
        __builtin_amdgcn_sched_barrier(0);   // keep ds_reads below the wait

        const float* qf = (const float*)&lds[buf][0];
        const float* vf = (const float*)&lds[buf][320];
        const int rb = row * 160;
        const int rx = row << 2;

        #pragma unroll
        for (int o = 0; o < 2; ++o) {
            const int c0 = (head0 + 8 * o) * 10;
            float sum = 0.f, dot = 0.f;
            #pragma unroll
            for (int d = 0; d < 10; ++d) {
                int fi = rb + ((c0 + d) ^ rx);    // swizzled read
                float e = __expf(tanh_rcp(qf[fi] * ksr[o][d]));
                sum += e;
                dot += e * vf[fi];
            }
            float res = dot * __builtin_amdgcn_rcpf(sum);
            (o ? obase1 : obase0)[(size_t)tt * TROWS] = res;
        }
        buf ^= 1;
    }
}

// ---------------------------------------------------------------------------
extern "C" void kernel_launch(void* const* d_in, const int* in_sizes, int n_in,
                              void* d_out, int out_size, void* d_ws, size_t ws_size,
                              hipStream_t stream) {
    const float* q = (const float*)d_in[0];
    const float* k = (const float*)d_in[1];
    const float* v = (const float*)d_in[2];
    // d_in[3] = W, d_in[4] = b : dead code (softmax over size-1 axis == 1)
    float* out  = (float*)d_out;
    float* ksum = (float*)d_ws;    // B*M floats = 40 KB

    zero_ws_kernel<<<dim3((BB * MM + 255) / 256), dim3(256), 0, stream>>>(ksum, BB * MM);
    ksum_kernel<<<dim3(10, 128), dim3(256), 0, stream>>>(k, ksum);
    attn_kernel<<<dim3(NBLK), dim3(64), 0, stream>>>(q, v, ksum, out);
}